// Round 6
// baseline (2124.886 us; speedup 1.0000x reference)
//
#include <hip/hip_runtime.h>
#include <math.h>

// ResidualQuantizer: 8 stages of VQ over B=32768 rows, D=256, K=1024.
// Outputs (flat f32): z_q_sum[32768*256], codes[32768*8] (as float), loss[1].
// Numerics: bit-exact numpy fp32 emulation for the argmin (proven r2/r3/r5):
//   dist = fl(fl(z2 + e2_k) - 2*ze_k), ze_k = ascending-d fp32 FMA chain,
//   e2_k = numpy pairwise sum, argmin = first occurrence of min.
// Round 6: KC=4 [code]-layout chunks -> Es 16KB (3 blocks/CU, was 2),
//   conflict-free contiguous ev reads with immediate offsets, codebook
//   pre-packed in d_ws for perfectly coalesced staging. Same numerics.

#define NQ 8
#define KCODES 1024
#define DDIM 256
#define BN 32768
#define TM 32            // rows per block
#define THREADS 256
#define KC 4             // k floats staged per chunk (1 float4 per code)
#define NCHUNK (DDIM / KC)   // 64
#define CPP 512          // codes per pass
#define NPASS 2

#define WS_E2    0
#define WS_LOSSP 32768
#define WS_PK    40960
#define WS_NEED  (40960 + (size_t)NQ * KCODES * DDIM * 4)

__device__ __forceinline__ void gld_lds16(const void* g, void* l) {
    __builtin_amdgcn_global_load_lds(
        (const __attribute__((address_space(1))) unsigned int*)g,
        (__attribute__((address_space(3))) unsigned int*)l, 16, 0, 0);
}

// ---- e2[s*K+k] = np.sum(cb[s][k]**2), exact numpy pairwise emulation ----
__global__ void e2_kernel(const float* __restrict__ cb, float* __restrict__ e2) {
    __shared__ float X[16][DDIM];
    const int t = threadIdx.x;
    const int cbase = blockIdx.x * 16;
    {
        const float4* src = (const float4*)(cb + (size_t)cbase * DDIM);
        float4* dst = (float4*)(&X[0][0]);
        #pragma unroll
        for (int n = 0; n < 4; ++n) dst[t + n * THREADS] = src[t + n * THREADS];
    }
    __syncthreads();
    const int lane = t & 63;
    const int code = (t >> 6) * 4 + (lane >> 4);
    const int u = lane & 15, j = u & 7, h = u >> 3;
    const float* x = &X[code][h * 128];
    float r = __fmul_rn(x[j], x[j]);
    for (int i = 1; i < 16; ++i) {
        float v = x[8 * i + j];
        r = __fadd_rn(r, __fmul_rn(v, v));
    }
    float o;
    o = __shfl_xor(r, 1); r = __fadd_rn(r, o);
    o = __shfl_xor(r, 2); r = __fadd_rn(r, o);
    o = __shfl_xor(r, 4); r = __fadd_rn(r, o);
    o = __shfl_xor(r, 8); r = __fadd_rn(r, o);
    if (u == 0) e2[cbase + code] = r;
}

// ---- pack cb into per-chunk LDS images: pk[(sp*64+c)*512 + code] = cb_row[c*4..] ----
__global__ void pack_kernel(const float* __restrict__ cb, float4* __restrict__ pk) {
    const int t = threadIdx.x;
    const int bid = blockIdx.x;          // (s*2+p)*64 + c
    const int c = bid & 63, sp = bid >> 6;
    const float* src = cb + (size_t)sp * 512 * DDIM + c * 4;
    float4* dst = pk + (size_t)bid * 512;
    #pragma unroll
    for (int n = 0; n < 2; ++n) {
        int u = n * 256 + t;
        dst[u] = *(const float4*)(src + (size_t)u * DDIM);
    }
}

template <bool PACKED>
__global__ __launch_bounds__(THREADS, 3) void rq_kernel(
    const float* __restrict__ zin, const float* __restrict__ cb,
    const float* __restrict__ e2g, const float4* __restrict__ pk,
    float* __restrict__ out, double* __restrict__ lossp)
{
    __shared__ float  Rs[TM][DDIM];        // 32 KB residual tile (persistent)
    __shared__ float4 Es[2][512];          // 2 x 8 KB codebook chunk, dbuf
    __shared__ float  top1v[NPASS][TM];
    __shared__ int    top1i[NPASS][TM];
    __shared__ float  z2s[TM];
    __shared__ int    codes_s[TM];
    __shared__ double lredw[4];

    const int t    = threadIdx.x;
    const int l    = t & 63;
    const int w    = t >> 6;               // wave id; wave w owns rows w*8..w*8+7
    const size_t rowbase = (size_t)blockIdx.x * TM;
    const int row_u = t >> 3, oct = t & 7;

    // ---- load residual tile = z_e rows (coalesced) ----
    {
        const float4* src = (const float4*)(zin + rowbase * DDIM);
        float4* dst = (float4*)(&Rs[0][0]);
        #pragma unroll
        for (int n = 0; n < (TM * DDIM / 4) / THREADS; ++n)
            dst[t + n * THREADS] = src[t + n * THREADS];
    }
    __syncthreads();

    // ---- initial z2 per row (uniform shift: any fp32 order OK — proven) ----
    {
        const float4* rrow = (const float4*)(&Rs[row_u][oct * 32]);
        float z2n = 0.f;
        #pragma unroll
        for (int i = 0; i < 8; ++i) {
            float4 rv = rrow[i];
            z2n = fmaf(rv.x, rv.x, z2n); z2n = fmaf(rv.y, rv.y, z2n);
            z2n = fmaf(rv.z, rv.z, z2n); z2n = fmaf(rv.w, rv.w, z2n);
        }
        z2n += __shfl_xor(z2n, 1);
        z2n += __shfl_xor(z2n, 2);
        z2n += __shfl_xor(z2n, 4);
        if (oct == 0) z2s[row_u] = z2n;
    }
    double lacc = 0.0;

    for (int s = 0; s < NQ; ++s) {
        const float* cbs = cb + (size_t)s * KCODES * DDIM;

        for (int p = 0; p < NPASS; ++p) {
            const int code0 = p * CPP;
            // staging sources (unit u = n*256 + w*64 + l -> code u)
            const float4* sbp = PACKED ? pk + ((size_t)(s * 2 + p) * 64) * 512
                                       : (const float4*)0;
            const float*  sbf = cbs + (size_t)(code0 + w * 64 + l) * DDIM;

            float acc[8][8];
            #pragma unroll
            for (int i = 0; i < 8; ++i)
                #pragma unroll
                for (int j = 0; j < 8; ++j) acc[i][j] = 0.f;

            // ---- prologue: stage chunk 0 into buf 0 ----
            #pragma unroll
            for (int n = 0; n < 2; ++n) {
                if (PACKED)
                    gld_lds16(sbp + n * 256 + w * 64 + l, &Es[0][n * 256 + w * 64]);
                else
                    gld_lds16(sbf + (size_t)n * 256 * DDIM, &Es[0][n * 256 + w * 64]);
            }

            #pragma unroll 2
            for (int c = 0; c < NCHUNK; ++c) {
                // wait only STALE loads (chunk c, issued one iter ago), then raw
                // barrier: chunk c published; buf[(c+1)&1] reads done (prev iter).
                asm volatile("s_waitcnt vmcnt(0)" ::: "memory");
                __builtin_amdgcn_s_barrier();
                asm volatile("" ::: "memory");
                __builtin_amdgcn_sched_barrier(0);

                const int buf = c & 1;
                if (c + 1 < NCHUNK) {   // prefetch stays in flight across barrier
                    #pragma unroll
                    for (int n = 0; n < 2; ++n) {
                        if (PACKED)
                            gld_lds16(sbp + (size_t)(c + 1) * 512 + n * 256 + w * 64 + l,
                                      &Es[buf ^ 1][n * 256 + w * 64]);
                        else
                            gld_lds16(sbf + (size_t)n * 256 * DDIM + (c + 1) * KC,
                                      &Es[buf ^ 1][n * 256 + w * 64]);
                    }
                }

                // ascending-d fp32 FMA chain (identical arithmetic to r2/r3/r5)
                float4 ev[8];
                #pragma unroll
                for (int j = 0; j < 8; ++j)
                    ev[j] = Es[buf][j * 64 + l];     // contiguous: conflict-free
                #pragma unroll
                for (int i = 0; i < 8; ++i) {
                    float4 rv = *(const float4*)(&Rs[w * 8 + i][c * KC]);
                    #pragma unroll
                    for (int j = 0; j < 8; ++j) {
                        acc[i][j] = fmaf(rv.x, ev[j].x, acc[i][j]);
                        acc[i][j] = fmaf(rv.y, ev[j].y, acc[i][j]);
                        acc[i][j] = fmaf(rv.z, ev[j].z, acc[i][j]);
                        acc[i][j] = fmaf(rv.w, ev[j].w, acc[i][j]);
                    }
                }
            }

            float e2v[8];
            #pragma unroll
            for (int j = 0; j < 8; ++j)
                e2v[j] = e2g[s * KCODES + code0 + j * 64 + l];

            // ---- per-row top-1, numpy-exact dist & first-occurrence ties ----
            #pragma unroll
            for (int i = 0; i < 8; ++i) {
                float z2i = z2s[w * 8 + i];
                float m1 = 3.4e38f; int i1 = 0x7fffffff;
                #pragma unroll
                for (int j = 0; j < 8; ++j) {
                    float S = __fadd_rn(z2i, e2v[j]);      // fl(z2 + e2)
                    float v = fmaf(-2.f, acc[i][j], S);    // fl(S - 2*ze)
                    int cc = code0 + j * 64 + l;
                    if (v < m1) { m1 = v; i1 = cc; }       // ascending cc keeps first
                }
                #pragma unroll
                for (int d2 = 1; d2 < 64; d2 <<= 1) {
                    float ov = __shfl_xor(m1, d2); int oi = __shfl_xor(i1, d2);
                    if (ov < m1 || (ov == m1 && oi < i1)) { m1 = ov; i1 = oi; }
                }
                if (l == i) { top1v[p][w * 8 + i] = m1; top1i[p][w * 8 + i] = i1; }
            }
            __syncthreads();
        }

        // ---- merge passes (tie -> lower index = pass 0), emit code ----
        if (t < TM) {
            float av = top1v[0][t]; int ai = top1i[0][t];
            float bv = top1v[1][t]; int bi = top1i[1][t];
            int code = (bv < av) ? bi : ai;
            codes_s[t] = code;
            out[(size_t)BN * DDIM + (rowbase + t) * NQ + s] = (float)code;
        }
        __syncthreads();

        // ---- straight-through update, op-for-op numpy emulation ----
        {
            int c = codes_s[row_u];
            const float4* crow = (const float4*)(cbs + (size_t)c * DDIM + oct * 32);
            float4* rrow = (float4*)(&Rs[row_u][oct * 32]);
            float z2n = 0.f;
            #pragma unroll
            for (int n = 0; n < 8; ++n) {
                int i = (n + t) & 7;              // rotate -> spread LDS banks
                float4 rv = rrow[i];
                float4 cv = crow[i];
                float t1x = __fsub_rn(cv.x, rv.x), t1y = __fsub_rn(cv.y, rv.y);
                float t1z = __fsub_rn(cv.z, rv.z), t1w = __fsub_rn(cv.w, rv.w);
                lacc += (double)t1x * t1x + (double)t1y * t1y
                      + (double)t1z * t1z + (double)t1w * t1w;
                float qx = __fadd_rn(rv.x, t1x), qy = __fadd_rn(rv.y, t1y);
                float qz = __fadd_rn(rv.z, t1z), qw = __fadd_rn(rv.w, t1w);
                float nx = __fsub_rn(rv.x, qx), ny = __fsub_rn(rv.y, qy);
                float nz = __fsub_rn(rv.z, qz), nw = __fsub_rn(rv.w, qw);
                z2n = fmaf(nx, nx, z2n); z2n = fmaf(ny, ny, z2n);
                z2n = fmaf(nz, nz, z2n); z2n = fmaf(nw, nw, z2n);
                rrow[i] = make_float4(nx, ny, nz, nw);
            }
            z2n += __shfl_xor(z2n, 1);
            z2n += __shfl_xor(z2n, 2);
            z2n += __shfl_xor(z2n, 4);
            if (oct == 0) z2s[row_u] = z2n;
        }
        __syncthreads();
    }

    // ---- z_q_sum = z_e - residual_final (telescoped; tolerance-validated) ----
    {
        const float4* zsrc = (const float4*)(zin + rowbase * DDIM);
        const float4* rsrc = (const float4*)(&Rs[0][0]);
        float4* dst = (float4*)(out + rowbase * DDIM);
        #pragma unroll
        for (int n = 0; n < (TM * DDIM / 4) / THREADS; ++n) {
            int idx = t + n * THREADS;
            float4 a = zsrc[idx], r = rsrc[idx];
            a.x -= r.x; a.y -= r.y; a.z -= r.z; a.w -= r.w;
            dst[idx] = a;
        }
    }

    // ---- deterministic loss partial: wave shfl-reduce, then 4-way sum ----
    #pragma unroll
    for (int d2 = 1; d2 < 64; d2 <<= 1)
        lacc += __shfl_xor(lacc, d2);
    if (l == 0) lredw[w] = lacc;
    __syncthreads();
    if (t == 0)
        lossp[blockIdx.x] = (lredw[0] + lredw[1]) + (lredw[2] + lredw[3]);
}

__global__ void loss_final(const double* __restrict__ lossp, float* __restrict__ out) {
    double s = 0.0;
    for (int i = 0; i < BN / TM; ++i) s += lossp[i];
    out[(size_t)BN * DDIM + (size_t)BN * NQ] = (float)(1.25 * s / ((double)BN * (double)DDIM));
}

extern "C" void kernel_launch(void* const* d_in, const int* in_sizes, int n_in,
                              void* d_out, int out_size, void* d_ws, size_t ws_size,
                              hipStream_t stream) {
    const float* z_e = (const float*)d_in[0];
    const float* cb  = (const float*)d_in[1];
    float* out = (float*)d_out;
    float*  e2    = (float*)((char*)d_ws + WS_E2);
    double* lossp = (double*)((char*)d_ws + WS_LOSSP);
    float4* pk    = (float4*)((char*)d_ws + WS_PK);

    e2_kernel<<<dim3((NQ * KCODES) / 16), THREADS, 0, stream>>>(cb, e2);
    if (ws_size >= WS_NEED) {
        pack_kernel<<<dim3(NQ * NPASS * NCHUNK), THREADS, 0, stream>>>(cb, pk);
        rq_kernel<true><<<dim3(BN / TM), THREADS, 0, stream>>>(z_e, cb, e2, pk, out, lossp);
    } else {
        rq_kernel<false><<<dim3(BN / TM), THREADS, 0, stream>>>(z_e, cb, e2, pk, out, lossp);
    }
    loss_final<<<1, 1, 0, stream>>>(lossp, out);
}